// Round 3
// baseline (347.438 us; speedup 1.0000x reference)
//
#include <hip/hip_runtime.h>
#include <math.h>

#define BB 32
#define SS 2048
#define DD 512
#define AD 512

#define BM 128
#define BN 128
#define BK 64    // A row (bf16): 64 bf16 = 128 B = 8 granules; B same

typedef __bf16 bf16;
typedef __attribute__((ext_vector_type(8))) __bf16 bf16x8;
typedef __attribute__((ext_vector_type(4))) __bf16 bf16x4;
typedef __attribute__((ext_vector_type(4))) float floatx4;

__device__ inline void async16(const void* g, void* l) {
    __builtin_amdgcn_global_load_lds(
        (const __attribute__((address_space(1))) unsigned int*)g,
        (__attribute__((address_space(3))) unsigned int*)l, 16, 0, 0);
}

// ---------------- K0: convert W2||W1 -> bf16 (2 MB total) ----------------
#define NW8 (AD * DD / 8)   // 32768 granules-of-8 per matrix
__global__ void convert_kernel(const float* __restrict__ W2,
                               const float* __restrict__ W1,
                               bf16* __restrict__ Wb) {
    int j = threadIdx.x + blockIdx.x * 256;          // 0..65535
    const float* src = (j < NW8) ? (W2 + (size_t)j * 8)
                                 : (W1 + (size_t)(j - NW8) * 8);
    const float4* s4 = (const float4*)src;
    float4 x = s4[0], y = s4[1];
    bf16x8 o;
    o[0] = (bf16)x.x; o[1] = (bf16)x.y; o[2] = (bf16)x.z; o[3] = (bf16)x.w;
    o[4] = (bf16)y.x; o[5] = (bf16)y.y; o[6] = (bf16)y.z; o[7] = (bf16)y.w;
    *(bf16x8*)(Wb + (size_t)j * 8) = o;
}

// ---------------- K1-fb: w1q for legacy fallback path --------------------
__global__ void w1q_kernel(const float* __restrict__ query,
                           const float* __restrict__ W1,
                           float* __restrict__ w1q) {
    int id = blockIdx.x;                 // 0..4095
    int b = id >> 7;
    int a = (id & 127) * 4 + (threadIdx.x >> 6);
    int lane = threadIdx.x & 63;
    const float4* q4 = (const float4*)(query + (size_t)b * DD) + lane * 2;
    const float4* w4 = (const float4*)(W1 + (size_t)a * DD) + lane * 2;
    float4 qa = q4[0], qb = q4[1];
    float4 wa = w4[0], wb = w4[1];
    float acc = qa.x * wa.x + qa.y * wa.y + qa.z * wa.z + qa.w * wa.w
              + qb.x * wb.x + qb.y * wb.y + qb.z * wb.z + qb.w * wb.w;
#pragma unroll
    for (int off = 32; off > 0; off >>= 1) acc += __shfl_down(acc, off);
    if (lane == 0) w1q[(size_t)b * AD + a] = acc;
}

// ---------------- K2: K-augmented MFMA GEMM + tanh/v epilogue -------------
// Computes scores = v . tanh(keys*W2^T + query*W1^T) with NO prep deps
// beyond the bf16 weight convert:
//  - chunks 0..7  : A = keys (reg-staged fp32->bf16, SINGLE 16KB buffer,
//                   loads issued at compute-top for c+1, cvt+ds_write after
//                   the read barrier -> no occupancy cost, latency hidden)
//  - chunks 8..15 : A-rows are all query[b] (broadcast) -> contribution is
//                   row-independent; accumulate with 4 MFMAs/ks into
//                   accW[ni] (af built straight from query, no LDS)
//  - B            : global_load_lds from Wb = [W2b | W1b], dbuf 2x16KB,
//                   issue for c+2 right after the read barrier
// LDS 48KB -> 3 blocks/CU (round-0 occupancy kept). XOR-8 granule swizzle
// throughout (measured 0 bank conflicts in rounds 0/2).
__global__ __launch_bounds__(256, 3)
void gemm_scores_mfma(const float* __restrict__ keys,
                      const bf16* __restrict__ Wb,
                      const float* __restrict__ query,
                      const float* __restrict__ v,
                      float* __restrict__ partial) {
    __shared__ bf16 a_lds[BM * BK];        // 16 KB, single
    __shared__ bf16 b_lds[2][BN * BK];     // 2 x 16 KB

    const int t    = threadIdx.x;
    const int lane = t & 63;
    const int w    = t >> 6;
    const int ml   = lane & 15;
    const int kg   = lane >> 4;

    // grid decode: lin -> (keys-tile kt, a_tile) with lin&7 == kt&7 (XCD)
    const int lin    = blockIdx.x;
    const int x8     = lin & 7;
    const int hi     = lin >> 3;
    const int a_tile = hi & 3;
    const int kt     = x8 + ((hi >> 2) << 3);   // 0..511
    const int b      = kt >> 4;
    const int s0     = (kt & 15) * BM;
    const int a0     = a_tile * BN;

    const int m_off = (w & 1) * 64;
    const int n_off = (w >> 1) * 64;

    const float* Ablk = keys + ((size_t)b * SS + s0) * DD;
    const bf16*  Bblk = Wb + (size_t)a0 * DD;
    const float* qrow = query + (size_t)b * DD;

    floatx4 acc[4][4];
    floatx4 accW[4];
#pragma unroll
    for (int mi = 0; mi < 4; ++mi)
#pragma unroll
        for (int ni = 0; ni < 4; ++ni)
            acc[mi][ni] = (floatx4)(0.f);
#pragma unroll
    for (int ni = 0; ni < 4; ++ni) accW[ni] = (floatx4)(0.f);

    // A staging geometry: granule u = t + 256*j, row r = u>>3, logical
    // col-granule cg = u&7, swizzled slot = cg ^ (r&7).
    int ar[4], ac8[4], acs[4];
#pragma unroll
    for (int j = 0; j < 4; ++j) {
        int u = t + 256 * j;
        ar[j]  = u >> 3;
        ac8[j] = (u & 7) * 8;
        acs[j] = ((u & 7) ^ (ar[j] & 7)) * 8;
    }

    float4 areg[4][2];

    // ---- prologue: A chunk0 (regs->LDS), B chunks 0,1 (async) ----
#pragma unroll
    for (int j = 0; j < 4; ++j) {
        const float* src = Ablk + (size_t)ar[j] * DD + ac8[j];
        areg[j][0] = *(const float4*)src;
        areg[j][1] = *(const float4*)(src + 4);
    }
#pragma unroll
    for (int i = 0; i < 4; ++i) {
        int g = t + 256 * i;
        int r = g >> 3, cs = (g & 7) ^ (r & 7);
        async16(Bblk + (size_t)r * DD + cs * 8,
                &b_lds[0][(256 * i + 64 * w) * 8]);
    }
#pragma unroll
    for (int i = 0; i < 4; ++i) {
        int g = t + 256 * i;
        int r = g >> 3, cs = (g & 7) ^ (r & 7);
        async16(Bblk + (size_t)r * DD + BK + cs * 8,
                &b_lds[1][(256 * i + 64 * w) * 8]);
    }
#pragma unroll
    for (int j = 0; j < 4; ++j) {
        bf16x8 o;
        o[0] = (bf16)areg[j][0].x; o[1] = (bf16)areg[j][0].y;
        o[2] = (bf16)areg[j][0].z; o[3] = (bf16)areg[j][0].w;
        o[4] = (bf16)areg[j][1].x; o[5] = (bf16)areg[j][1].y;
        o[6] = (bf16)areg[j][1].z; o[7] = (bf16)areg[j][1].w;
        *(bf16x8*)&a_lds[ar[j] * BK + acs[j]] = o;
    }
    __syncthreads();

    for (int c = 0; c < 16; ++c) {
        const int ca = c + 1;
        // T14 early-issue: next keys chunk -> regs (covered by compute)
        if (ca < 8) {
            const int d0a = ca * BK;
#pragma unroll
            for (int j = 0; j < 4; ++j) {
                const float* src = Ablk + (size_t)ar[j] * DD + d0a + ac8[j];
                areg[j][0] = *(const float4*)src;
                areg[j][1] = *(const float4*)(src + 4);
            }
        }

        if (c < 8) {
            // full tile: keys x W2
#pragma unroll
            for (int ks = 0; ks < 2; ++ks) {
                bf16x8 af[4], bfr[4];
#pragma unroll
                for (int mi = 0; mi < 4; ++mi) {
                    int R = m_off + mi * 16 + ml;
                    int p = (ks * 4 + kg) ^ (R & 7);
                    af[mi] = *(const bf16x8*)&a_lds[R * BK + p * 8];
                }
#pragma unroll
                for (int ni = 0; ni < 4; ++ni) {
                    int R = n_off + ni * 16 + ml;
                    int p = (ks * 4 + kg) ^ (R & 7);
                    bfr[ni] = *(const bf16x8*)&b_lds[c & 1][R * BK + p * 8];
                }
#pragma unroll
                for (int mi = 0; mi < 4; ++mi)
#pragma unroll
                    for (int ni = 0; ni < 4; ++ni)
                        acc[mi][ni] = __builtin_amdgcn_mfma_f32_16x16x32_bf16(
                            af[mi], bfr[ni], acc[mi][ni], 0, 0, 0);
            }
        } else {
            // aug range: query x W1 -> row-independent, 4 MFMAs/ks
            const int dq = (c - 8) * BK;
            float4 q0a = *(const float4*)(qrow + dq + kg * 8);
            float4 q0b = *(const float4*)(qrow + dq + kg * 8 + 4);
            float4 q1a = *(const float4*)(qrow + dq + 32 + kg * 8);
            float4 q1b = *(const float4*)(qrow + dq + 32 + kg * 8 + 4);
#pragma unroll
            for (int ks = 0; ks < 2; ++ks) {
                float4 qa = ks ? q1a : q0a;
                float4 qb = ks ? q1b : q0b;
                bf16x8 af;
                af[0] = (bf16)qa.x; af[1] = (bf16)qa.y;
                af[2] = (bf16)qa.z; af[3] = (bf16)qa.w;
                af[4] = (bf16)qb.x; af[5] = (bf16)qb.y;
                af[6] = (bf16)qb.z; af[7] = (bf16)qb.w;
                bf16x8 bfr[4];
#pragma unroll
                for (int ni = 0; ni < 4; ++ni) {
                    int R = n_off + ni * 16 + ml;
                    int p = (ks * 4 + kg) ^ (R & 7);
                    bfr[ni] = *(const bf16x8*)&b_lds[c & 1][R * BK + p * 8];
                }
#pragma unroll
                for (int ni = 0; ni < 4; ++ni)
                    accW[ni] = __builtin_amdgcn_mfma_f32_16x16x32_bf16(
                        af, bfr[ni], accW[ni], 0, 0, 0);
            }
        }

        __builtin_amdgcn_sched_barrier(0);
        __syncthreads();   // reads(c) done; A-loads(ca) drained (covered)

        // stage B for c+2 into the buffer just freed (L2-hot weights)
        if (c + 2 <= 15) {
            const int cn2  = c + 2;
            const size_t koff = (cn2 >= 8) ? (size_t)AD * DD : 0;
            const int d0b = (cn2 & 7) * BK;
#pragma unroll
            for (int i = 0; i < 4; ++i) {
                int g = t + 256 * i;
                int r = g >> 3, cs = (g & 7) ^ (r & 7);
                async16(Bblk + koff + (size_t)r * DD + d0b + cs * 8,
                        &b_lds[c & 1][(256 * i + 64 * w) * 8]);
            }
        }
        // deferred A cvt + ds_write for next keys chunk
        if (ca < 8) {
#pragma unroll
            for (int j = 0; j < 4; ++j) {
                bf16x8 o;
                o[0] = (bf16)areg[j][0].x; o[1] = (bf16)areg[j][0].y;
                o[2] = (bf16)areg[j][0].z; o[3] = (bf16)areg[j][0].w;
                o[4] = (bf16)areg[j][1].x; o[5] = (bf16)areg[j][1].y;
                o[6] = (bf16)areg[j][1].z; o[7] = (bf16)areg[j][1].w;
                *(bf16x8*)&a_lds[ar[j] * BK + acs[j]] = o;
            }
        }
        __syncthreads();   // writes visible; short drain
    }

    // epilogue: x = acc + accW (w1q via MFMA); tanh; v-weight; quad reduce
    float va[4];
#pragma unroll
    for (int ni = 0; ni < 4; ++ni) va[ni] = v[a0 + n_off + ni * 16 + ml];
    const int slot = a_tile * 2 + (w >> 1);
#pragma unroll
    for (int mi = 0; mi < 4; ++mi) {
#pragma unroll
        for (int reg = 0; reg < 4; ++reg) {
            float p = 0.f;
#pragma unroll
            for (int ni = 0; ni < 4; ++ni) {
                float x = acc[mi][ni][reg] + accW[ni][0];
                float th = 1.f - 2.f / (1.f + __expf(2.f * x));
                p = fmaf(th, va[ni], p);
            }
            p += __shfl_xor(p, 1);
            p += __shfl_xor(p, 2);
            p += __shfl_xor(p, 4);
            p += __shfl_xor(p, 8);
            if (ml == 0) {
                int row = m_off + mi * 16 + kg * 4 + reg;
                partial[((size_t)b * SS + s0 + row) * 8 + slot] = p;
            }
        }
    }
}

// ---------------- K2-fallback (legacy, small-ws path) ---------------------
#define FBK 32
#define FLDK (FBK + 8)
__global__ __launch_bounds__(256, 2)
void gemm_scores_fallback(const float* __restrict__ keys,
                          const float* __restrict__ W2,
                          const float* __restrict__ w1q,
                          const float* __restrict__ v,
                          float* __restrict__ partial) {
    __shared__ bf16 a_lds[BM][FLDK];
    __shared__ bf16 b_lds[BN][FLDK];
    __shared__ float s_red[BM];

    const int t    = threadIdx.x;
    const int lane = t & 63;
    const int w    = t >> 6;
    const int ml   = lane & 15;
    const int kg   = lane >> 4;
    const int b    = blockIdx.z;
    const int s0   = blockIdx.x * BM;
    const int a0   = blockIdx.y * BN;
    const int m_off = (w & 1) * 64;
    const int n_off = (w >> 1) * 64;

    const float* Ablk = keys + ((size_t)b * SS + s0) * DD;
    const float* Bblk = W2 + (size_t)a0 * DD;

    if (t < BM) s_red[t] = 0.f;

    floatx4 acc[4][4];
#pragma unroll
    for (int mi = 0; mi < 4; ++mi)
#pragma unroll
        for (int ni = 0; ni < 4; ++ni)
            acc[mi][ni] = (floatx4)(0.f);

    float4 ga[4], gb[4];
#pragma unroll
    for (int i = 0; i < 4; ++i) {
        int idx = t + 256 * i;
        int r = idx >> 3, c = idx & 7;
        ga[i] = *(const float4*)(Ablk + (size_t)r * DD + c * 4);
        gb[i] = *(const float4*)(Bblk + (size_t)r * DD + c * 4);
    }

    for (int chunk = 0; chunk < DD / FBK; ++chunk) {
        __syncthreads();
#pragma unroll
        for (int i = 0; i < 4; ++i) {
            int idx = t + 256 * i;
            int r = idx >> 3, c = idx & 7;
            bf16x4 pa, pb;
            pa[0] = (bf16)ga[i].x; pa[1] = (bf16)ga[i].y;
            pa[2] = (bf16)ga[i].z; pa[3] = (bf16)ga[i].w;
            pb[0] = (bf16)gb[i].x; pb[1] = (bf16)gb[i].y;
            pb[2] = (bf16)gb[i].z; pb[3] = (bf16)gb[i].w;
            *(bf16x4*)&a_lds[r][c * 4] = pa;
            *(bf16x4*)&b_lds[r][c * 4] = pb;
        }
        __syncthreads();
        if (chunk < DD / FBK - 1) {
            int d0 = (chunk + 1) * FBK;
#pragma unroll
            for (int i = 0; i < 4; ++i) {
                int idx = t + 256 * i;
                int r = idx >> 3, c = idx & 7;
                ga[i] = *(const float4*)(Ablk + (size_t)r * DD + d0 + c * 4);
                gb[i] = *(const float4*)(Bblk + (size_t)r * DD + d0 + c * 4);
            }
        }
        bf16x8 af[4], bfr[4];
#pragma unroll
        for (int mi = 0; mi < 4; ++mi)
            af[mi] = *(const bf16x8*)&a_lds[m_off + mi * 16 + ml][kg * 8];
#pragma unroll
        for (int ni = 0; ni < 4; ++ni)
            bfr[ni] = *(const bf16x8*)&b_lds[n_off + ni * 16 + ml][kg * 8];
#pragma unroll
        for (int mi = 0; mi < 4; ++mi)
#pragma unroll
            for (int ni = 0; ni < 4; ++ni)
                acc[mi][ni] = __builtin_amdgcn_mfma_f32_16x16x32_bf16(
                    af[mi], bfr[ni], acc[mi][ni], 0, 0, 0);
    }

    float w1qa[4], va[4];
#pragma unroll
    for (int ni = 0; ni < 4; ++ni) {
        int a = a0 + n_off + ni * 16 + ml;
        w1qa[ni] = w1q[(size_t)b * AD + a];
        va[ni]   = v[a];
    }
#pragma unroll
    for (int mi = 0; mi < 4; ++mi) {
#pragma unroll
        for (int reg = 0; reg < 4; ++reg) {
            float p = 0.f;
#pragma unroll
            for (int ni = 0; ni < 4; ++ni) {
                float x = acc[mi][ni][reg] + w1qa[ni];
                float th = 1.f - 2.f / (1.f + __expf(2.f * x));
                p = fmaf(th, va[ni], p);
            }
            p += __shfl_xor(p, 1);
            p += __shfl_xor(p, 2);
            p += __shfl_xor(p, 4);
            p += __shfl_xor(p, 8);
            if (ml == 0)
                atomicAdd(&s_red[m_off + mi * 16 + kg * 4 + reg], p);
        }
    }
    __syncthreads();
    if (t < BM)
        partial[(((size_t)b * SS) + s0 + t) * 8 + blockIdx.y * 2] = s_red[t];
}

// ---------------- K3: inline mask probe + combine + masked softmax --------
__global__ void softmax_kernel(const float* __restrict__ partial,
                               const void* __restrict__ mask,
                               float* __restrict__ out) {
    const int b = blockIdx.x;
    const int t = threadIdx.x;
    __shared__ float rmax[4], rsum[4];
    __shared__ int s_bytes;
    const int wid = t >> 6, lane = t & 63;

    // mask dtype probe: u8 iff any nonzero byte at global index %4 != 0
    if (t == 0) s_bytes = 0;
    __syncthreads();
    {
        const uint4* m16 = (const uint4*)mask;
        unsigned pr = 0;
#pragma unroll
        for (int k = 0; k < 16; ++k) {
            uint4 x = m16[t + 256 * k];   // covers first 64 KB
            pr |= (x.x | x.y | x.z | x.w) & 0xFFFFFF00u;
        }
        if (pr) s_bytes = 1;
    }
    __syncthreads();
    const int bytes = s_bytes;
    const unsigned char* m8  = (const unsigned char*)mask;
    const int*           m32 = (const int*)mask;

    float sv[8]; int mv[8];
#pragma unroll
    for (int k = 0; k < 8; ++k) {
        int i = t + 256 * k;
        const float4* p4 = (const float4*)(partial + ((size_t)b * SS + i) * 8);
        float4 pa = p4[0], pb = p4[1];
        sv[k] = ((pa.x + pa.y) + (pa.z + pa.w)) + ((pb.x + pb.y) + (pb.z + pb.w));
        mv[k] = bytes ? (int)m8[(size_t)b * SS + i]
                      : m32[(size_t)b * SS + i];
    }

    float mx = -INFINITY;
#pragma unroll
    for (int k = 0; k < 8; ++k) mx = fmaxf(mx, mv[k] ? sv[k] : -INFINITY);
#pragma unroll
    for (int off = 32; off > 0; off >>= 1) mx = fmaxf(mx, __shfl_xor(mx, off));
    if (lane == 0) rmax[wid] = mx;
    __syncthreads();
    mx = fmaxf(fmaxf(rmax[0], rmax[1]), fmaxf(rmax[2], rmax[3]));

    float ev[8]; float sum = 0.f;
#pragma unroll
    for (int k = 0; k < 8; ++k) {
        ev[k] = mv[k] ? __expf(sv[k] - mx) : 0.f;
        sum += ev[k];
    }
#pragma unroll
    for (int off = 32; off > 0; off >>= 1) sum += __shfl_xor(sum, off);
    if (lane == 0) rsum[wid] = sum;
    __syncthreads();
    sum = (rsum[0] + rsum[1]) + (rsum[2] + rsum[3]);
    float inv = 1.f / sum;
#pragma unroll
    for (int k = 0; k < 8; ++k)
        out[(size_t)b * SS + t + 256 * k] = ev[k] * inv;
}

extern "C" void kernel_launch(void* const* d_in, const int* in_sizes, int n_in,
                              void* d_out, int out_size, void* d_ws, size_t ws_size,
                              hipStream_t stream) {
    const float* query = (const float*)d_in[0];
    const float* keys  = (const float*)d_in[1];
    const void*  mask  = d_in[2];
    const float* W1    = (const float*)d_in[3];
    const float* W2    = (const float*)d_in[4];
    const float* v     = (const float*)d_in[5];
    float* out = (float*)d_out;

    char* wsb = (char*)d_ws;
    // main layout: [pad 256][partial 2M][Wb = W2b|W1b 2M]
    float* partial = (float*)(wsb + 256);
    bf16*  Wb      = (bf16*)(wsb + 256 + 2097152);
    size_t need_main = 256 + 2097152 + (size_t)2 * AD * DD * 2;

    if (ws_size >= need_main) {
        convert_kernel<<<256, 256, 0, stream>>>(W2, W1, Wb);
        gemm_scores_mfma<<<(SS / BM) * (AD / BN) * BB, 256, 0, stream>>>(
            keys, Wb, query, v, partial);
        softmax_kernel<<<BB, 256, 0, stream>>>(partial, mask, out);
    } else {
        // legacy layout: [pad 256][w1q 64K][partial 2M]
        float* w1q        = (float*)(wsb + 256);
        float* partial_fb = (float*)(wsb + 256 + 65536);
        hipMemsetAsync(partial_fb, 0, (size_t)BB * SS * 8 * 4, stream);
        w1q_kernel<<<4096, 256, 0, stream>>>(query, W1, w1q);
        gemm_scores_fallback<<<dim3(SS / BM, AD / BN, BB), 256, 0, stream>>>(
            keys, W2, w1q, v, partial_fb);
        softmax_kernel<<<BB, 256, 0, stream>>>(partial_fb, mask, out);
    }
}

// Round 4
// 244.367 us; speedup vs baseline: 1.4218x; 1.4218x over previous
//
#include <hip/hip_runtime.h>
#include <math.h>

#define BB 32
#define SS 2048
#define DD 512
#define AD 512

#define BM 128
#define BN 128
#define BK 64    // A row (bf16): 64 bf16 = 128 B = 8 granules; B same

typedef __bf16 bf16;
typedef __attribute__((ext_vector_type(8))) __bf16 bf16x8;
typedef __attribute__((ext_vector_type(4))) __bf16 bf16x4;
typedef __attribute__((ext_vector_type(4))) float floatx4;

__device__ inline void async16(const void* g, void* l) {
    __builtin_amdgcn_global_load_lds(
        (const __attribute__((address_space(1))) unsigned int*)g,
        (__attribute__((address_space(3))) unsigned int*)l, 16, 0, 0);
}

// ---------------- K1: fused prep (round-0 verbatim) ----------------
// blocks [0, NCV)             : fp32->bf16 convert of W2 (1 MB only)
// blocks [NCV, NCV+64)        : mask dtype probe
// blocks [NCV+64, NCV+64+4096): w1q[b][a] = dot(query[b,:], W1[a,:])
#define NW8 (AD * DD / 8)
#define NCV (NW8 / 256)   // 128
__global__ void prep_kernel(const float* __restrict__ W2,
                            bf16* __restrict__ W2b,
                            const unsigned char* __restrict__ m8,
                            int* __restrict__ flag,
                            const float* __restrict__ query,
                            const float* __restrict__ W1,
                            float* __restrict__ w1q) {
    const int bid = blockIdx.x;
    if (bid < NCV) {
        int j = threadIdx.x + bid * 256;
        const float4* s4 = (const float4*)W2 + (size_t)j * 2;
        float4 x = s4[0], y = s4[1];
        bf16x8 o;
        o[0] = (bf16)x.x; o[1] = (bf16)x.y; o[2] = (bf16)x.z; o[3] = (bf16)x.w;
        o[4] = (bf16)y.x; o[5] = (bf16)y.y; o[6] = (bf16)y.z; o[7] = (bf16)y.w;
        *(bf16x8*)(W2b + (size_t)j * 8) = o;
    } else if (bid < NCV + 64) {
        int t = threadIdx.x + (bid - NCV) * 256;
        int any = 0;
        for (int i = t; i < BB * SS; i += 64 * 256)
            if ((i & 3) && m8[i]) any = 1;
        if (__any(any)) {
            if ((threadIdx.x & 63) == 0) atomicOr(flag, 1);
        }
    } else {
        int id = bid - NCV - 64;           // 0..4095
        int b = id >> 7;
        int a = (id & 127) * 4 + (threadIdx.x >> 6);
        int lane = threadIdx.x & 63;
        const float4* q4 = (const float4*)(query + (size_t)b * DD) + lane * 2;
        const float4* w4 = (const float4*)(W1 + (size_t)a * DD) + lane * 2;
        float4 qa = q4[0], qb = q4[1];
        float4 wa = w4[0], wb = w4[1];
        float acc = qa.x * wa.x + qa.y * wa.y + qa.z * wa.z + qa.w * wa.w
                  + qb.x * wb.x + qb.y * wb.y + qb.z * wb.z + qb.w * wb.w;
#pragma unroll
        for (int off = 32; off > 0; off >>= 1) acc += __shfl_down(acc, off);
        if (lane == 0) w1q[(size_t)b * AD + a] = acc;
    }
}

// ---------------- K2: hybrid-pipelined MFMA GEMM + tanh/v epilogue --------
// Round-0 skeleton (BK=64, 8 chunks, 32 MFMA/phase, XOR-8 swizzle, 48 KB
// LDS -> 3 blocks/CU) with the barrier drains fixed:
//  - A (keys): reg-staged fp32->bf16 (cvt ONCE), SINGLE 16 KB bf16 buffer.
//    Loads for c+1 issued right after the top barrier; consumed by the
//    deferred cvt+ds_write AFTER the raw mid barrier (counted vmcnt).
//  - B (W2b): global_load_lds, DOUBLE buffered 2x16 KB. Asyncs for c+1
//    issued after the top barrier, drained at the NEXT top barrier ->
//    full-chunk latency coverage.
//  - mid barrier = s_waitcnt lgkmcnt(0) + raw s_barrier (NOT __syncthreads)
//    so in-flight VMEM is NOT drained there (rule #18 sched_barrier fences).
__global__ __launch_bounds__(256, 3)
void gemm_scores_mfma(const float* __restrict__ keys,
                      const bf16* __restrict__ W2b,
                      const float* __restrict__ w1q,
                      const float* __restrict__ v,
                      float* __restrict__ partial) {
    __shared__ bf16 a_lds[BM * BK];        // 16 KB, single
    __shared__ bf16 b_lds[2][BN * BK];     // 2 x 16 KB

    const int t    = threadIdx.x;
    const int lane = t & 63;
    const int w    = t >> 6;
    const int ml   = lane & 15;
    const int kg   = lane >> 4;

    // grid decode: lin -> (keys-tile kt, a_tile) with lin&7 == kt&7 (XCD)
    const int lin    = blockIdx.x;
    const int x8     = lin & 7;
    const int hi     = lin >> 3;
    const int a_tile = hi & 3;
    const int kt     = x8 + ((hi >> 2) << 3);   // 0..511
    const int b      = kt >> 4;
    const int s0     = (kt & 15) * BM;
    const int a0     = a_tile * BN;

    const int m_off = (w & 1) * 64;
    const int n_off = (w >> 1) * 64;

    const float* Ablk = keys + ((size_t)b * SS + s0) * DD;
    const bf16*  Bblk = W2b + (size_t)a0 * DD;

    floatx4 acc[4][4];
#pragma unroll
    for (int mi = 0; mi < 4; ++mi)
#pragma unroll
        for (int ni = 0; ni < 4; ++ni)
            acc[mi][ni] = (floatx4)(0.f);

    // A staging geometry: granule u = t + 256*j, row r = u>>3, logical
    // col-granule cg = u&7 (8 fp32 -> 8 bf16 = 1 granule), swizzled slot
    // cs = cg ^ (r&7). (R2-verified: 0 bank conflicts, correct numerics.)
    int ar[4], ac8[4], acs[4];
#pragma unroll
    for (int j = 0; j < 4; ++j) {
        int u = t + 256 * j;
        ar[j]  = u >> 3;
        ac8[j] = (u & 7) * 8;
        acs[j] = ((u & 7) ^ (ar[j] & 7)) * 8;
    }

    float4 areg[4][2];

    // ---- prologue: A(0) -> regs, B(0) async -> b_lds[0], cvt+write A(0) --
#pragma unroll
    for (int j = 0; j < 4; ++j) {
        const float* src = Ablk + (size_t)ar[j] * DD + ac8[j];
        areg[j][0] = *(const float4*)src;
        areg[j][1] = *(const float4*)(src + 4);
    }
#pragma unroll
    for (int i = 0; i < 4; ++i) {
        int g = t + 256 * i;
        int r = g >> 3, cs = (g & 7) ^ (r & 7);
        async16(Bblk + (size_t)r * DD + cs * 8,
                &b_lds[0][(256 * i + 64 * w) * 8]);
    }
#pragma unroll
    for (int j = 0; j < 4; ++j) {
        bf16x8 o;
        o[0] = (bf16)areg[j][0].x; o[1] = (bf16)areg[j][0].y;
        o[2] = (bf16)areg[j][0].z; o[3] = (bf16)areg[j][0].w;
        o[4] = (bf16)areg[j][1].x; o[5] = (bf16)areg[j][1].y;
        o[6] = (bf16)areg[j][1].z; o[7] = (bf16)areg[j][1].w;
        *(bf16x8*)&a_lds[ar[j] * BK + acs[j]] = o;
    }

    const int NCHUNK = DD / BK;   // 8
    for (int c = 0; c < NCHUNK; ++c) {
        const int cur = c & 1;
        const int nxt = cur ^ 1;
        // top barrier: drains B(c) asyncs (issued a full chunk ago) and
        // A(c) ds_writes (lgkm, short)
        __syncthreads();

        if (c + 1 < NCHUNK) {
            const int d0 = (c + 1) * BK;
            // A loads first (consumed soonest, lowest vmcnt slots)
#pragma unroll
            for (int j = 0; j < 4; ++j) {
                const float* src = Ablk + (size_t)ar[j] * DD + d0 + ac8[j];
                areg[j][0] = *(const float4*)src;
                areg[j][1] = *(const float4*)(src + 4);
            }
            // B asyncs -> freed buffer, drained at next top barrier
#pragma unroll
            for (int i = 0; i < 4; ++i) {
                int g = t + 256 * i;
                int r = g >> 3, cs = (g & 7) ^ (r & 7);
                async16(Bblk + (size_t)r * DD + d0 + cs * 8,
                        &b_lds[nxt][(256 * i + 64 * w) * 8]);
            }
        }
        __builtin_amdgcn_sched_barrier(0);   // pin issues before MFMA cluster

        // frag reads + 32 MFMA from a_lds / b_lds[cur]
#pragma unroll
        for (int ks = 0; ks < 2; ++ks) {
            bf16x8 af[4], bfr[4];
#pragma unroll
            for (int mi = 0; mi < 4; ++mi) {
                int R = m_off + mi * 16 + ml;
                int p = (ks * 4 + kg) ^ (R & 7);
                af[mi] = *(const bf16x8*)&a_lds[R * BK + p * 8];
            }
#pragma unroll
            for (int ni = 0; ni < 4; ++ni) {
                int R = n_off + ni * 16 + ml;
                int p = (ks * 4 + kg) ^ (R & 7);
                bfr[ni] = *(const bf16x8*)&b_lds[cur][R * BK + p * 8];
            }
#pragma unroll
            for (int mi = 0; mi < 4; ++mi)
#pragma unroll
                for (int ni = 0; ni < 4; ++ni)
                    acc[mi][ni] = __builtin_amdgcn_mfma_f32_16x16x32_bf16(
                        af[mi], bfr[ni], acc[mi][ni], 0, 0, 0);
        }

        // mid barrier: all waves' a_lds reads done; VMEM stays in flight
        __builtin_amdgcn_sched_barrier(0);
        asm volatile("s_waitcnt lgkmcnt(0)" ::: "memory");
        __builtin_amdgcn_sched_barrier(0);
        __builtin_amdgcn_s_barrier();
        __builtin_amdgcn_sched_barrier(0);

        // deferred A cvt + ds_write for c+1 (compiler emits counted vmcnt:
        // only the 8 A-loads must land; the 4 B-asyncs may stay in flight)
        if (c + 1 < NCHUNK) {
#pragma unroll
            for (int j = 0; j < 4; ++j) {
                bf16x8 o;
                o[0] = (bf16)areg[j][0].x; o[1] = (bf16)areg[j][0].y;
                o[2] = (bf16)areg[j][0].z; o[3] = (bf16)areg[j][0].w;
                o[4] = (bf16)areg[j][1].x; o[5] = (bf16)areg[j][1].y;
                o[6] = (bf16)areg[j][1].z; o[7] = (bf16)areg[j][1].w;
                *(bf16x8*)&a_lds[ar[j] * BK + acs[j]] = o;
            }
        }
    }

    // epilogue (round-0 verbatim): tanh + v-weight; quad shuffle-reduce;
    // direct global store of partial[(b,s)*8 + a_tile*2 + n_half].
    float w1qa[4], va[4];
#pragma unroll
    for (int ni = 0; ni < 4; ++ni) {
        int a = a0 + n_off + ni * 16 + ml;
        w1qa[ni] = w1q[(size_t)b * AD + a];
        va[ni]   = v[a];
    }
    const int slot = a_tile * 2 + (w >> 1);
#pragma unroll
    for (int mi = 0; mi < 4; ++mi) {
#pragma unroll
        for (int reg = 0; reg < 4; ++reg) {
            float p = 0.f;
#pragma unroll
            for (int ni = 0; ni < 4; ++ni) {
                float x = acc[mi][ni][reg] + w1qa[ni];
                float th = 1.f - 2.f / (1.f + __expf(2.f * x));
                p = fmaf(th, va[ni], p);
            }
            p += __shfl_xor(p, 1);
            p += __shfl_xor(p, 2);
            p += __shfl_xor(p, 4);
            p += __shfl_xor(p, 8);
            if (ml == 0) {
                int row = m_off + mi * 16 + kg * 4 + reg;
                partial[((size_t)b * SS + s0 + row) * 8 + slot] = p;
            }
        }
    }
}

// ---------------- K2-fallback (round-0 verbatim) --------------------------
#define FBK 32
#define FLDK (FBK + 8)
__global__ __launch_bounds__(256, 2)
void gemm_scores_fallback(const float* __restrict__ keys,
                          const float* __restrict__ W2,
                          const float* __restrict__ w1q,
                          const float* __restrict__ v,
                          float* __restrict__ partial) {
    __shared__ bf16 a_lds[BM][FLDK];
    __shared__ bf16 b_lds[BN][FLDK];
    __shared__ float s_red[BM];

    const int t    = threadIdx.x;
    const int lane = t & 63;
    const int w    = t >> 6;
    const int ml   = lane & 15;
    const int kg   = lane >> 4;
    const int b    = blockIdx.z;
    const int s0   = blockIdx.x * BM;
    const int a0   = blockIdx.y * BN;
    const int m_off = (w & 1) * 64;
    const int n_off = (w >> 1) * 64;

    const float* Ablk = keys + ((size_t)b * SS + s0) * DD;
    const float* Bblk = W2 + (size_t)a0 * DD;

    if (t < BM) s_red[t] = 0.f;

    floatx4 acc[4][4];
#pragma unroll
    for (int mi = 0; mi < 4; ++mi)
#pragma unroll
        for (int ni = 0; ni < 4; ++ni)
            acc[mi][ni] = (floatx4)(0.f);

    float4 ga[4], gb[4];
#pragma unroll
    for (int i = 0; i < 4; ++i) {
        int idx = t + 256 * i;
        int r = idx >> 3, c = idx & 7;
        ga[i] = *(const float4*)(Ablk + (size_t)r * DD + c * 4);
        gb[i] = *(const float4*)(Bblk + (size_t)r * DD + c * 4);
    }

    for (int chunk = 0; chunk < DD / FBK; ++chunk) {
        __syncthreads();
#pragma unroll
        for (int i = 0; i < 4; ++i) {
            int idx = t + 256 * i;
            int r = idx >> 3, c = idx & 7;
            bf16x4 pa, pb;
            pa[0] = (bf16)ga[i].x; pa[1] = (bf16)ga[i].y;
            pa[2] = (bf16)ga[i].z; pa[3] = (bf16)ga[i].w;
            pb[0] = (bf16)gb[i].x; pb[1] = (bf16)gb[i].y;
            pb[2] = (bf16)gb[i].z; pb[3] = (bf16)gb[i].w;
            *(bf16x4*)&a_lds[r][c * 4] = pa;
            *(bf16x4*)&b_lds[r][c * 4] = pb;
        }
        __syncthreads();
        if (chunk < DD / FBK - 1) {
            int d0 = (chunk + 1) * FBK;
#pragma unroll
            for (int i = 0; i < 4; ++i) {
                int idx = t + 256 * i;
                int r = idx >> 3, c = idx & 7;
                ga[i] = *(const float4*)(Ablk + (size_t)r * DD + d0 + c * 4);
                gb[i] = *(const float4*)(Bblk + (size_t)r * DD + d0 + c * 4);
            }
        }
        bf16x8 af[4], bfr[4];
#pragma unroll
        for (int mi = 0; mi < 4; ++mi)
            af[mi] = *(const bf16x8*)&a_lds[m_off + mi * 16 + ml][kg * 8];
#pragma unroll
        for (int ni = 0; ni < 4; ++ni)
            bfr[ni] = *(const bf16x8*)&b_lds[n_off + ni * 16 + ml][kg * 8];
#pragma unroll
        for (int mi = 0; mi < 4; ++mi)
#pragma unroll
            for (int ni = 0; ni < 4; ++ni)
                acc[mi][ni] = __builtin_amdgcn_mfma_f32_16x16x32_bf16(
                    af[mi], bfr[ni], acc[mi][ni], 0, 0, 0);
    }

    float w1qa[4], va[4];
#pragma unroll
    for (int ni = 0; ni < 4; ++ni) {
        int a = a0 + n_off + ni * 16 + ml;
        w1qa[ni] = w1q[(size_t)b * AD + a];
        va[ni]   = v[a];
    }
#pragma unroll
    for (int mi = 0; mi < 4; ++mi) {
#pragma unroll
        for (int reg = 0; reg < 4; ++reg) {
            float p = 0.f;
#pragma unroll
            for (int ni = 0; ni < 4; ++ni) {
                float x = acc[mi][ni][reg] + w1qa[ni];
                float th = 1.f - 2.f / (1.f + __expf(2.f * x));
                p = fmaf(th, va[ni], p);
            }
            p += __shfl_xor(p, 1);
            p += __shfl_xor(p, 2);
            p += __shfl_xor(p, 4);
            p += __shfl_xor(p, 8);
            if (ml == 0)
                atomicAdd(&s_red[m_off + mi * 16 + kg * 4 + reg], p);
        }
    }
    __syncthreads();
    if (t < BM)
        partial[(((size_t)b * SS) + s0 + t) * 8 + blockIdx.y * 2] = s_red[t];
}

// ---------------- K3: combine 8 partials + masked softmax (round-0) -------
__global__ void softmax_kernel(const float* __restrict__ partial,
                               const int* __restrict__ mask_i32,
                               const unsigned char* __restrict__ mask_u8,
                               const int* __restrict__ flag,
                               float* __restrict__ out) {
    const int b = blockIdx.x;
    const int t = threadIdx.x;
    __shared__ float rmax[4], rsum[4];
    const int wid = t >> 6, lane = t & 63;

    float sv[8]; int mv[8];
    const int bytes = (*flag != 0);
#pragma unroll
    for (int k = 0; k < 8; ++k) {
        int i = t + 256 * k;
        const float4* p4 = (const float4*)(partial + ((size_t)b * SS + i) * 8);
        float4 pa = p4[0], pb = p4[1];
        sv[k] = ((pa.x + pa.y) + (pa.z + pa.w)) + ((pb.x + pb.y) + (pb.z + pb.w));
        mv[k] = bytes ? (int)mask_u8[(size_t)b * SS + i]
                      : mask_i32[(size_t)b * SS + i];
    }

    float mx = -INFINITY;
#pragma unroll
    for (int k = 0; k < 8; ++k) mx = fmaxf(mx, mv[k] ? sv[k] : -INFINITY);
#pragma unroll
    for (int off = 32; off > 0; off >>= 1) mx = fmaxf(mx, __shfl_xor(mx, off));
    if (lane == 0) rmax[wid] = mx;
    __syncthreads();
    mx = fmaxf(fmaxf(rmax[0], rmax[1]), fmaxf(rmax[2], rmax[3]));

    float ev[8]; float sum = 0.f;
#pragma unroll
    for (int k = 0; k < 8; ++k) {
        ev[k] = mv[k] ? __expf(sv[k] - mx) : 0.f;
        sum += ev[k];
    }
#pragma unroll
    for (int off = 32; off > 0; off >>= 1) sum += __shfl_xor(sum, off);
    if (lane == 0) rsum[wid] = sum;
    __syncthreads();
    sum = (rsum[0] + rsum[1]) + (rsum[2] + rsum[3]);
    float inv = 1.f / sum;
#pragma unroll
    for (int k = 0; k < 8; ++k)
        out[(size_t)b * SS + t + 256 * k] = ev[k] * inv;
}

extern "C" void kernel_launch(void* const* d_in, const int* in_sizes, int n_in,
                              void* d_out, int out_size, void* d_ws, size_t ws_size,
                              hipStream_t stream) {
    const float* query = (const float*)d_in[0];
    const float* keys  = (const float*)d_in[1];
    const void*  mask  = d_in[2];
    const float* W1    = (const float*)d_in[3];
    const float* W2    = (const float*)d_in[4];
    const float* v     = (const float*)d_in[5];
    float* out = (float*)d_out;

    // ws layout (bytes): [flag 256][w1q 64K][partial 2M][W2b 0.5M]
    char* wsb = (char*)d_ws;
    int*   flag    = (int*)wsb;
    float* w1q     = (float*)(wsb + 256);
    float* partial = (float*)(wsb + 256 + 65536);
    bf16*  W2b     = (bf16*)(wsb + 256 + 65536 + 2097152);
    size_t need = 256 + 65536 + 2097152 + (size_t)AD * DD * 2;

    hipMemsetAsync(flag, 0, 4, stream);
    if (ws_size >= need) {
        prep_kernel<<<NCV + 64 + 4096, 256, 0, stream>>>(
            W2, W2b, (const unsigned char*)mask, flag, query, W1, w1q);
        gemm_scores_mfma<<<(SS / BM) * (AD / BN) * BB, 256, 0, stream>>>(
            keys, W2b, w1q, v, partial);
    } else {
        hipMemsetAsync(partial, 0, (size_t)BB * SS * 8 * 4, stream);
        prep_kernel<<<NCV + 64 + 4096, 256, 0, stream>>>(
            W2, W2b, (const unsigned char*)mask, flag, query, W1, w1q);
        gemm_scores_fallback<<<dim3(SS / BM, AD / BN, BB), 256, 0, stream>>>(
            keys, W2, w1q, v, partial);
    }
    softmax_kernel<<<BB, 256, 0, stream>>>(partial, (const int*)mask,
                                           (const unsigned char*)mask, flag, out);
}